// Round 9
// baseline (198.553 us; speedup 1.0000x reference)
//
#include <hip/hip_runtime.h>
#include <math.h>

// ZINB decoder, round 9.
// r8 post-mortem: TA line-visits no longer binding (~0.24/cyc); wall 18.7
// cyc/edge vs ~7.5 ideal -> exposed latency. Two fixes:
//  (1) reduction xor4 via DPP row_half_mirror (0x141) instead of ds_swizzle:
//      after xor1/xor2 (quad_perm), half-mirror completes the 8-lane sum
//      entirely on the VALU pipe (no lgkmcnt stall per sub-phase).
//  (2) explicit 1-deep software pipeline: sub-phase j+1's index+row loads
//      issue before sub-phase j's compute, giving the TA a standing queue.
// Structure otherwise = r8: 8 lanes/edge, f16-packed rows (1 line/row),
// v_pk_mul_f16 + v_dot2_f32_f16, bijective lane->edge perm for a 64-wide
// activation tail with line-coalesced stores.

typedef _Float16 h2 __attribute__((ext_vector_type(2)));

#if __has_builtin(__builtin_amdgcn_fdot2)
__device__ __forceinline__ float fdot2f(h2 a, h2 b, float c) {
    return __builtin_amdgcn_fdot2(a, b, c, false);
}
#else
__device__ __forceinline__ float fdot2f(h2 a, h2 b, float c) {
    return fmaf((float)a.x, (float)b.x, fmaf((float)a.y, (float)b.y, c));
}
#endif

// 8-lane sum, pure DPP (VALU pipe only): xor1, xor2 (quad_perm), half-mirror.
__device__ __forceinline__ float red8(float x) {
    int t;
    t = __builtin_amdgcn_mov_dpp(__float_as_int(x), 0xB1, 0xF, 0xF, true);  // quad_perm [1,0,3,2] = xor1
    x += __int_as_float(t);
    t = __builtin_amdgcn_mov_dpp(__float_as_int(x), 0x4E, 0xF, 0xF, true);  // quad_perm [2,3,0,1] = xor2
    x += __int_as_float(t);
    t = __builtin_amdgcn_mov_dpp(__float_as_int(x), 0x141, 0xF, 0xF, true); // row_half_mirror = "xor-half" within 8
    x += __int_as_float(t);
    return x;
}

__device__ __forceinline__ unsigned pack2h(float lo, float hi) {
    h2 p = {(_Float16)lo, (_Float16)hi};
    return __builtin_bit_cast(unsigned, p);
}

// ---------------- pack kernel: f32 rows -> f16 rows in d_ws ----------------
__global__ __launch_bounds__(256) void zinb_pack_kernel(
    const float4* __restrict__ c_src, const float4* __restrict__ g_src,
    uint4* __restrict__ c_dst, uint4* __restrict__ g_dst,
    int n_c_groups, int n_total_groups)   // group = 8 floats -> one uint4
{
    const int i = (int)(blockIdx.x * blockDim.x + threadIdx.x);
    if (i >= n_total_groups) return;
    const float4* src; uint4* dst; int j;
    if (i < n_c_groups) { src = c_src; dst = c_dst; j = i; }
    else                { src = g_src; dst = g_dst; j = i - n_c_groups; }
    const float4 a = src[2 * j];
    const float4 b = src[2 * j + 1];
    uint4 o;
    o.x = pack2h(a.x, a.y);
    o.y = pack2h(a.z, a.w);
    o.z = pack2h(b.x, b.y);
    o.w = pack2h(b.z, b.w);
    dst[j] = o;
}

// ---------------- main kernel: 8 lanes per edge, pipelined f16 gathers ----------------
__global__ __launch_bounds__(256, 8) void zinb_edge_f16_kernel(
    const uint4* __restrict__ c_pack,   // [n_cells][8] uint4 (64 f16)
    const uint4* __restrict__ g_pack,   // [n_genes][8]
    const float* __restrict__ cs_factor,
    const float* __restrict__ gs_factor,
    const int* __restrict__ edge_u,
    const int* __restrict__ edge_v,
    const float* __restrict__ W_mean, const float* __restrict__ b_mean,
    const float* __restrict__ W_disp, const float* __restrict__ b_disp,
    const float* __restrict__ W_pi,   const float* __restrict__ b_pi,
    float* __restrict__ out_mu,
    float* __restrict__ out_disp,
    float* __restrict__ out_pi,
    int n_edges)
{
    const int lane = (int)(threadIdx.x & 63);
    const int k    = lane & 7;    // chunk within row (elements 8k..8k+7)
    const int grp  = lane >> 3;   // edge within octet

    // Per-lane weight fragments for chunk k (fixed for kernel lifetime).
    h2 wm[4], wd[4], wp[4];
    #pragma unroll
    for (int i = 0; i < 4; ++i) {
        wm[i] = (h2){(_Float16)W_mean[8 * k + 2 * i], (_Float16)W_mean[8 * k + 2 * i + 1]};
        wd[i] = (h2){(_Float16)W_disp[8 * k + 2 * i], (_Float16)W_disp[8 * k + 2 * i + 1]};
        wp[i] = (h2){(_Float16)W_pi  [8 * k + 2 * i], (_Float16)W_pi  [8 * k + 2 * i + 1]};
    }
    const float bm = b_mean[0], bd = b_disp[0], bp = b_pi[0];

    const int perm = (k << 3) | grp;          // this lane's tail-edge offset

    int e0 = (int)(blockIdx.x * blockDim.x + threadIdx.x) & ~63;  // wave base
    const int stride = (int)(gridDim.x * blockDim.x);

    for (; e0 < n_edges; e0 += stride) {
        // ---- tail-operand prefetch (latency hidden under the 8 sub-phases) ----
        const int et  = e0 + perm;
        const int etc = (et < n_edges) ? et : (n_edges - 1);
        const int ut = edge_u[etc];
        const int vt = edge_v[etc];
        const float cs_t = cs_factor[ut];
        const float gs_t = gs_factor[vt];

        // ---- pipeline prologue: sub-phase 0 loads ----
        int ej0 = e0 + grp;
        if (ej0 >= n_edges) ej0 = n_edges - 1;
        uint4 cu4 = c_pack[(size_t)edge_u[ej0] * 8 + k];
        uint4 gu4 = g_pack[(size_t)edge_v[ej0] * 8 + k];

        float pmk = 0.f, pdk = 0.f, ppk = 0.f;

        #pragma unroll
        for (int j = 0; j < 8; ++j) {
            // issue next sub-phase's loads before this sub-phase's compute
            uint4 ncu, ngu;
            if (j < 7) {
                int en = e0 + 8 * (j + 1) + grp;
                if (en >= n_edges) en = n_edges - 1;
                ncu = c_pack[(size_t)edge_u[en] * 8 + k];
                ngu = g_pack[(size_t)edge_v[en] * 8 + k];
            }

            const h2 c0 = __builtin_bit_cast(h2, cu4.x), g0 = __builtin_bit_cast(h2, gu4.x);
            const h2 c1 = __builtin_bit_cast(h2, cu4.y), g1 = __builtin_bit_cast(h2, gu4.y);
            const h2 c2 = __builtin_bit_cast(h2, cu4.z), g2 = __builtin_bit_cast(h2, gu4.z);
            const h2 c3 = __builtin_bit_cast(h2, cu4.w), g3 = __builtin_bit_cast(h2, gu4.w);
            const h2 h0 = c0 * g0;                 // v_pk_mul_f16
            const h2 h1 = c1 * g1;
            const h2 hh2 = c2 * g2;
            const h2 h3 = c3 * g3;

            float pm = 0.f, pd = 0.f, pp = 0.f;
            pm = fdot2f(h0, wm[0], pm); pm = fdot2f(h1, wm[1], pm);
            pm = fdot2f(hh2, wm[2], pm); pm = fdot2f(h3, wm[3], pm);
            pd = fdot2f(h0, wd[0], pd); pd = fdot2f(h1, wd[1], pd);
            pd = fdot2f(hh2, wd[2], pd); pd = fdot2f(h3, wd[3], pd);
            pp = fdot2f(h0, wp[0], pp); pp = fdot2f(h1, wp[1], pp);
            pp = fdot2f(hh2, wp[2], pp); pp = fdot2f(h3, wp[3], pp);

            pm = red8(pm);
            pd = red8(pd);
            pp = red8(pp);

            if (k == j) { pmk = pm; pdk = pd; ppk = pp; }  // lane's own edge

            cu4 = ncu; gu4 = ngu;
        }

        // ---- tail: 64 lanes, one edge each ----
        const float mu_ = __builtin_amdgcn_rcpf(1.f + __expf(-(pmk + bm)));
        const float pi_ = __builtin_amdgcn_rcpf(1.f + __expf(-(ppk + bp)));

        const float sx = gs_t * (pdk + bd);
        const float sp = fmaxf(sx, 0.f) + __logf(1.f + __expf(-fabsf(sx)));
        const float disp = fminf(fmaxf(sp, 1e-4f), 1e4f);

        const float mu = cs_t * fminf(fmaxf(__expf(gs_t * mu_) - 1.f, 1e-5f), 1e6f);

        if (et < n_edges) {
            __builtin_nontemporal_store(mu,   out_mu + et);
            __builtin_nontemporal_store(disp, out_disp + et);
            __builtin_nontemporal_store(pi_,  out_pi + et);
        }
    }
}

// ---------------- f32 fallback (round-3/5 kernel, proven) ----------------
__global__ __launch_bounds__(256) void zinb_edge_f32_kernel(
    const float* __restrict__ c_feat,
    const float* __restrict__ g_feat,
    const float* __restrict__ cs_factor,
    const float* __restrict__ gs_factor,
    const int* __restrict__ edge_u,
    const int* __restrict__ edge_v,
    const float* __restrict__ W_mean, const float* __restrict__ b_mean,
    const float* __restrict__ W_disp, const float* __restrict__ b_disp,
    const float* __restrict__ W_pi,   const float* __restrict__ b_pi,
    float* __restrict__ out_mu,
    float* __restrict__ out_disp,
    float* __restrict__ out_pi,
    int n_edges)
{
    __shared__ float4 wlds[48];
    {
        const int t = threadIdx.x;
        if (t < 48) {
            const int which = t / 16;
            const int kk    = t % 16;
            const float4* src = (which == 0) ? (const float4*)W_mean
                              : (which == 1) ? (const float4*)W_disp
                                             : (const float4*)W_pi;
            wlds[kk * 3 + which] = src[kk];
        }
    }
    __syncthreads();

    const float bm = b_mean[0], bd = b_disp[0], bp = b_pi[0];
    const float4* __restrict__ c4 = (const float4*)c_feat;
    const float4* __restrict__ g4 = (const float4*)g_feat;

    const int tid    = (int)(blockIdx.x * blockDim.x + threadIdx.x);
    const int stride = (int)(gridDim.x * blockDim.x);

    for (int e = tid; e < n_edges; e += stride) {
        const int u = edge_u[e];
        const int v = edge_v[e];
        const float4* __restrict__ cb = c4 + (size_t)u * 16;
        const float4* __restrict__ gb = g4 + (size_t)v * 16;

        float pm = 0.f, pd = 0.f, pp = 0.f;
        #pragma unroll
        for (int kk = 0; kk < 16; ++kk) {
            const float4 cc = cb[kk];
            const float4 gg = gb[kk];
            const float4 wmv = wlds[kk * 3 + 0];
            const float4 wdv = wlds[kk * 3 + 1];
            const float4 wpv = wlds[kk * 3 + 2];
            const float hx = cc.x * gg.x;
            const float hy = cc.y * gg.y;
            const float hz = cc.z * gg.z;
            const float hw = cc.w * gg.w;
            pm = fmaf(hx, wmv.x, fmaf(hy, wmv.y, fmaf(hz, wmv.z, fmaf(hw, wmv.w, pm))));
            pd = fmaf(hx, wdv.x, fmaf(hy, wdv.y, fmaf(hz, wdv.z, fmaf(hw, wdv.w, pd))));
            pp = fmaf(hx, wpv.x, fmaf(hy, wpv.y, fmaf(hz, wpv.z, fmaf(hw, wpv.w, pp))));
        }

        const float gs = gs_factor[v];
        const float cs = cs_factor[u];
        const float mu_ = __builtin_amdgcn_rcpf(1.f + __expf(-(pm + bm)));
        const float pi_ = __builtin_amdgcn_rcpf(1.f + __expf(-(pp + bp)));
        const float sx = gs * (pd + bd);
        const float sp = fmaxf(sx, 0.f) + __logf(1.f + __expf(-fabsf(sx)));
        const float disp = fminf(fmaxf(sp, 1e-4f), 1e4f);
        const float mu = cs * fminf(fmaxf(__expf(gs * mu_) - 1.f, 1e-5f), 1e6f);

        out_mu[e]   = mu;
        out_disp[e] = disp;
        out_pi[e]   = pi_;
    }
}

extern "C" void kernel_launch(void* const* d_in, const int* in_sizes, int n_in,
                              void* d_out, int out_size, void* d_ws, size_t ws_size,
                              hipStream_t stream) {
    const float* c_feat = (const float*)d_in[0];
    const float* g_feat = (const float*)d_in[1];
    const float* cs     = (const float*)d_in[2];
    const float* gs     = (const float*)d_in[3];
    const int*   eu     = (const int*)d_in[4];
    const int*   ev     = (const int*)d_in[5];
    const float* Wm     = (const float*)d_in[6];
    const float* bm     = (const float*)d_in[7];
    const float* Wd     = (const float*)d_in[8];
    const float* bd     = (const float*)d_in[9];
    const float* Wp     = (const float*)d_in[10];
    const float* bp     = (const float*)d_in[11];

    const int E       = in_sizes[4];
    const int n_cells = in_sizes[0] / 64;
    const int n_genes = in_sizes[1] / 64;

    float* out_mu   = (float*)d_out;
    float* out_disp = out_mu + E;
    float* out_pi   = out_mu + 2 * (size_t)E;

    const size_t c_bytes = (size_t)n_cells * 64 * 2;   // f16 rows (128 B each)
    const size_t g_bytes = (size_t)n_genes * 64 * 2;

    if (ws_size >= c_bytes + g_bytes) {
        uint4* c_pack = (uint4*)d_ws;
        uint4* g_pack = (uint4*)((char*)d_ws + c_bytes);

        const int n_c_groups = n_cells * 8;            // 8 floats per group
        const int n_total    = n_c_groups + n_genes * 8;
        dim3 pgrid((n_total + 255) / 256), pblock(256);
        hipLaunchKernelGGL(zinb_pack_kernel, pgrid, pblock, 0, stream,
                           (const float4*)c_feat, (const float4*)g_feat,
                           c_pack, g_pack, n_c_groups, n_total);

        dim3 grid(2048), block(256);
        hipLaunchKernelGGL(zinb_edge_f16_kernel, grid, block, 0, stream,
                           c_pack, g_pack, cs, gs, eu, ev,
                           Wm, bm, Wd, bd, Wp, bp,
                           out_mu, out_disp, out_pi, E);
    } else {
        dim3 grid(2048), block(256);
        hipLaunchKernelGGL(zinb_edge_f32_kernel, grid, block, 0, stream,
                           c_feat, g_feat, cs, gs, eu, ev,
                           Wm, bm, Wd, bd, Wp, bp,
                           out_mu, out_disp, out_pi, E);
    }
}

// Round 10
// 184.653 us; speedup vs baseline: 1.0753x; 1.0753x over previous
//
#include <hip/hip_runtime.h>
#include <math.h>

// ZINB decoder, round 10.
// r9 post-mortem: forcing 8 waves/SIMD (VGPR=32) starved the pipeline ->
// compiler serialized the idx->row dependent chain; occupancy rose but time
// regressed (91->102us). Revised model: bound = per-wave dependent-load
// window depth, not wave count. This round: deep STATIC window -- hoist all
// 16 idx loads, then all 16 row gathers (8 subphases x c,g) into registers
// before any compute (r6-style latency hiding + r8-style line coalescing).
// ~64 VGPR of buffers, no min-wave launch bound. Reduction stays pure-DPP.

typedef _Float16 h2 __attribute__((ext_vector_type(2)));

#if __has_builtin(__builtin_amdgcn_fdot2)
__device__ __forceinline__ float fdot2f(h2 a, h2 b, float c) {
    return __builtin_amdgcn_fdot2(a, b, c, false);
}
#else
__device__ __forceinline__ float fdot2f(h2 a, h2 b, float c) {
    return fmaf((float)a.x, (float)b.x, fmaf((float)a.y, (float)b.y, c));
}
#endif

// 8-lane sum, pure DPP (VALU pipe only): xor1, xor2 (quad_perm), half-mirror.
__device__ __forceinline__ float red8(float x) {
    int t;
    t = __builtin_amdgcn_mov_dpp(__float_as_int(x), 0xB1, 0xF, 0xF, true);  // quad_perm [1,0,3,2] = xor1
    x += __int_as_float(t);
    t = __builtin_amdgcn_mov_dpp(__float_as_int(x), 0x4E, 0xF, 0xF, true);  // quad_perm [2,3,0,1] = xor2
    x += __int_as_float(t);
    t = __builtin_amdgcn_mov_dpp(__float_as_int(x), 0x141, 0xF, 0xF, true); // row_half_mirror: xor4 within 8
    x += __int_as_float(t);
    return x;
}

__device__ __forceinline__ unsigned pack2h(float lo, float hi) {
    h2 p = {(_Float16)lo, (_Float16)hi};
    return __builtin_bit_cast(unsigned, p);
}

// ---------------- pack kernel: f32 rows -> f16 rows in d_ws ----------------
__global__ __launch_bounds__(256) void zinb_pack_kernel(
    const float4* __restrict__ c_src, const float4* __restrict__ g_src,
    uint4* __restrict__ c_dst, uint4* __restrict__ g_dst,
    int n_c_groups, int n_total_groups)   // group = 8 floats -> one uint4
{
    const int i = (int)(blockIdx.x * blockDim.x + threadIdx.x);
    if (i >= n_total_groups) return;
    const float4* src; uint4* dst; int j;
    if (i < n_c_groups) { src = c_src; dst = c_dst; j = i; }
    else                { src = g_src; dst = g_dst; j = i - n_c_groups; }
    const float4 a = src[2 * j];
    const float4 b = src[2 * j + 1];
    uint4 o;
    o.x = pack2h(a.x, a.y);
    o.y = pack2h(a.z, a.w);
    o.z = pack2h(b.x, b.y);
    o.w = pack2h(b.z, b.w);
    dst[j] = o;
}

// -------- main kernel: 8 lanes/edge, deep static gather window --------
__global__ __launch_bounds__(256) void zinb_edge_f16_kernel(
    const uint4* __restrict__ c_pack,   // [n_cells][8] uint4 (64 f16)
    const uint4* __restrict__ g_pack,   // [n_genes][8]
    const float* __restrict__ cs_factor,
    const float* __restrict__ gs_factor,
    const int* __restrict__ edge_u,
    const int* __restrict__ edge_v,
    const float* __restrict__ W_mean, const float* __restrict__ b_mean,
    const float* __restrict__ W_disp, const float* __restrict__ b_disp,
    const float* __restrict__ W_pi,   const float* __restrict__ b_pi,
    float* __restrict__ out_mu,
    float* __restrict__ out_disp,
    float* __restrict__ out_pi,
    int n_edges)
{
    const int lane = (int)(threadIdx.x & 63);
    const int k    = lane & 7;    // chunk within row (elements 8k..8k+7)
    const int grp  = lane >> 3;   // edge within octet

    // Per-lane weight fragments for chunk k (fixed for kernel lifetime).
    h2 wm[4], wd[4], wp[4];
    #pragma unroll
    for (int i = 0; i < 4; ++i) {
        wm[i] = (h2){(_Float16)W_mean[8 * k + 2 * i], (_Float16)W_mean[8 * k + 2 * i + 1]};
        wd[i] = (h2){(_Float16)W_disp[8 * k + 2 * i], (_Float16)W_disp[8 * k + 2 * i + 1]};
        wp[i] = (h2){(_Float16)W_pi  [8 * k + 2 * i], (_Float16)W_pi  [8 * k + 2 * i + 1]};
    }
    const float bm = b_mean[0], bd = b_disp[0], bp = b_pi[0];

    const int perm = (k << 3) | grp;          // this lane's tail-edge offset

    int e0 = (int)(blockIdx.x * blockDim.x + threadIdx.x) & ~63;  // wave base
    const int stride = (int)(gridDim.x * blockDim.x);

    for (; e0 < n_edges; e0 += stride) {
        // ---- phase 1: all 16 index loads (independent, broadcast-coalesced) ----
        int ua[8], va[8];
        #pragma unroll
        for (int j = 0; j < 8; ++j) {
            int ej = e0 + 8 * j + grp;
            if (ej >= n_edges) ej = n_edges - 1;   // whole octet clamps together
            ua[j] = edge_u[ej];
            va[j] = edge_v[ej];
        }

        // ---- phase 2: all 16 row gathers issued back-to-back ----
        uint4 cu[8], gu[8];
        #pragma unroll
        for (int j = 0; j < 8; ++j) {
            cu[j] = c_pack[(size_t)ua[j] * 8 + k];
            gu[j] = g_pack[(size_t)va[j] * 8 + k];
        }

        // ---- tail operands (overlap with row-gather latency) ----
        const int et  = e0 + perm;
        const int etc = (et < n_edges) ? et : (n_edges - 1);
        const float cs_t = cs_factor[edge_u[etc]];
        const float gs_t = gs_factor[edge_v[etc]];

        // ---- phase 3: 8 compute sub-phases ----
        float pmk = 0.f, pdk = 0.f, ppk = 0.f;

        #pragma unroll
        for (int j = 0; j < 8; ++j) {
            const h2 c0 = __builtin_bit_cast(h2, cu[j].x), g0 = __builtin_bit_cast(h2, gu[j].x);
            const h2 c1 = __builtin_bit_cast(h2, cu[j].y), g1 = __builtin_bit_cast(h2, gu[j].y);
            const h2 c2 = __builtin_bit_cast(h2, cu[j].z), g2 = __builtin_bit_cast(h2, gu[j].z);
            const h2 c3 = __builtin_bit_cast(h2, cu[j].w), g3 = __builtin_bit_cast(h2, gu[j].w);
            const h2 h0 = c0 * g0;                 // v_pk_mul_f16
            const h2 h1 = c1 * g1;
            const h2 hh2 = c2 * g2;
            const h2 h3 = c3 * g3;

            float pm = 0.f, pd = 0.f, pp = 0.f;
            pm = fdot2f(h0, wm[0], pm); pm = fdot2f(h1, wm[1], pm);
            pm = fdot2f(hh2, wm[2], pm); pm = fdot2f(h3, wm[3], pm);
            pd = fdot2f(h0, wd[0], pd); pd = fdot2f(h1, wd[1], pd);
            pd = fdot2f(hh2, wd[2], pd); pd = fdot2f(h3, wd[3], pd);
            pp = fdot2f(h0, wp[0], pp); pp = fdot2f(h1, wp[1], pp);
            pp = fdot2f(hh2, wp[2], pp); pp = fdot2f(h3, wp[3], pp);

            pm = red8(pm);
            pd = red8(pd);
            pp = red8(pp);

            if (k == j) { pmk = pm; pdk = pd; ppk = pp; }  // lane's own edge
        }

        // ---- tail: 64 lanes, one edge each ----
        const float mu_ = __builtin_amdgcn_rcpf(1.f + __expf(-(pmk + bm)));
        const float pi_ = __builtin_amdgcn_rcpf(1.f + __expf(-(ppk + bp)));

        const float sx = gs_t * (pdk + bd);
        const float sp = fmaxf(sx, 0.f) + __logf(1.f + __expf(-fabsf(sx)));
        const float disp = fminf(fmaxf(sp, 1e-4f), 1e4f);

        const float mu = cs_t * fminf(fmaxf(__expf(gs_t * mu_) - 1.f, 1e-5f), 1e6f);

        if (et < n_edges) {
            __builtin_nontemporal_store(mu,   out_mu + et);
            __builtin_nontemporal_store(disp, out_disp + et);
            __builtin_nontemporal_store(pi_,  out_pi + et);
        }
    }
}

// ---------------- f32 fallback (round-3/5 kernel, proven) ----------------
__global__ __launch_bounds__(256) void zinb_edge_f32_kernel(
    const float* __restrict__ c_feat,
    const float* __restrict__ g_feat,
    const float* __restrict__ cs_factor,
    const float* __restrict__ gs_factor,
    const int* __restrict__ edge_u,
    const int* __restrict__ edge_v,
    const float* __restrict__ W_mean, const float* __restrict__ b_mean,
    const float* __restrict__ W_disp, const float* __restrict__ b_disp,
    const float* __restrict__ W_pi,   const float* __restrict__ b_pi,
    float* __restrict__ out_mu,
    float* __restrict__ out_disp,
    float* __restrict__ out_pi,
    int n_edges)
{
    __shared__ float4 wlds[48];
    {
        const int t = threadIdx.x;
        if (t < 48) {
            const int which = t / 16;
            const int kk    = t % 16;
            const float4* src = (which == 0) ? (const float4*)W_mean
                              : (which == 1) ? (const float4*)W_disp
                                             : (const float4*)W_pi;
            wlds[kk * 3 + which] = src[kk];
        }
    }
    __syncthreads();

    const float bm = b_mean[0], bd = b_disp[0], bp = b_pi[0];
    const float4* __restrict__ c4 = (const float4*)c_feat;
    const float4* __restrict__ g4 = (const float4*)g_feat;

    const int tid    = (int)(blockIdx.x * blockDim.x + threadIdx.x);
    const int stride = (int)(gridDim.x * blockDim.x);

    for (int e = tid; e < n_edges; e += stride) {
        const int u = edge_u[e];
        const int v = edge_v[e];
        const float4* __restrict__ cb = c4 + (size_t)u * 16;
        const float4* __restrict__ gb = g4 + (size_t)v * 16;

        float pm = 0.f, pd = 0.f, pp = 0.f;
        #pragma unroll
        for (int kk = 0; kk < 16; ++kk) {
            const float4 cc = cb[kk];
            const float4 gg = gb[kk];
            const float4 wmv = wlds[kk * 3 + 0];
            const float4 wdv = wlds[kk * 3 + 1];
            const float4 wpv = wlds[kk * 3 + 2];
            const float hx = cc.x * gg.x;
            const float hy = cc.y * gg.y;
            const float hz = cc.z * gg.z;
            const float hw = cc.w * gg.w;
            pm = fmaf(hx, wmv.x, fmaf(hy, wmv.y, fmaf(hz, wmv.z, fmaf(hw, wmv.w, pm))));
            pd = fmaf(hx, wdv.x, fmaf(hy, wdv.y, fmaf(hz, wdv.z, fmaf(hw, wdv.w, pd))));
            pp = fmaf(hx, wpv.x, fmaf(hy, wpv.y, fmaf(hz, wpv.z, fmaf(hw, wpv.w, pp))));
        }

        const float gs = gs_factor[v];
        const float cs = cs_factor[u];
        const float mu_ = __builtin_amdgcn_rcpf(1.f + __expf(-(pm + bm)));
        const float pi_ = __builtin_amdgcn_rcpf(1.f + __expf(-(pp + bp)));
        const float sx = gs * (pd + bd);
        const float sp = fmaxf(sx, 0.f) + __logf(1.f + __expf(-fabsf(sx)));
        const float disp = fminf(fmaxf(sp, 1e-4f), 1e4f);
        const float mu = cs * fminf(fmaxf(__expf(gs * mu_) - 1.f, 1e-5f), 1e6f);

        out_mu[e]   = mu;
        out_disp[e] = disp;
        out_pi[e]   = pi_;
    }
}

extern "C" void kernel_launch(void* const* d_in, const int* in_sizes, int n_in,
                              void* d_out, int out_size, void* d_ws, size_t ws_size,
                              hipStream_t stream) {
    const float* c_feat = (const float*)d_in[0];
    const float* g_feat = (const float*)d_in[1];
    const float* cs     = (const float*)d_in[2];
    const float* gs     = (const float*)d_in[3];
    const int*   eu     = (const int*)d_in[4];
    const int*   ev     = (const int*)d_in[5];
    const float* Wm     = (const float*)d_in[6];
    const float* bm     = (const float*)d_in[7];
    const float* Wd     = (const float*)d_in[8];
    const float* bd     = (const float*)d_in[9];
    const float* Wp     = (const float*)d_in[10];
    const float* bp     = (const float*)d_in[11];

    const int E       = in_sizes[4];
    const int n_cells = in_sizes[0] / 64;
    const int n_genes = in_sizes[1] / 64;

    float* out_mu   = (float*)d_out;
    float* out_disp = out_mu + E;
    float* out_pi   = out_mu + 2 * (size_t)E;

    const size_t c_bytes = (size_t)n_cells * 64 * 2;   // f16 rows (128 B each)
    const size_t g_bytes = (size_t)n_genes * 64 * 2;

    if (ws_size >= c_bytes + g_bytes) {
        uint4* c_pack = (uint4*)d_ws;
        uint4* g_pack = (uint4*)((char*)d_ws + c_bytes);

        const int n_c_groups = n_cells * 8;            // 8 floats per group
        const int n_total    = n_c_groups + n_genes * 8;
        dim3 pgrid((n_total + 255) / 256), pblock(256);
        hipLaunchKernelGGL(zinb_pack_kernel, pgrid, pblock, 0, stream,
                           (const float4*)c_feat, (const float4*)g_feat,
                           c_pack, g_pack, n_c_groups, n_total);

        dim3 grid(2048), block(256);
        hipLaunchKernelGGL(zinb_edge_f16_kernel, grid, block, 0, stream,
                           c_pack, g_pack, cs, gs, eu, ev,
                           Wm, bm, Wd, bd, Wp, bp,
                           out_mu, out_disp, out_pi, E);
    } else {
        dim3 grid(2048), block(256);
        hipLaunchKernelGGL(zinb_edge_f32_kernel, grid, block, 0, stream,
                           c_feat, g_feat, cs, gs, eu, ev,
                           Wm, bm, Wd, bd, Wp, bp,
                           out_mu, out_disp, out_pi, E);
    }
}

// Round 11
// 182.672 us; speedup vs baseline: 1.0869x; 1.0108x over previous
//
#include <hip/hip_runtime.h>
#include <math.h>

// ZINB decoder, round 11.
// r10 post-mortem: compiler sank the gather window (VGPR=40, ~6 loads in
// flight) -> stuck at 0.23 line-misses/cyc/CU vs the 0.55-0.6 equilibrium r6
// demonstrated. This round FORCES the window: phase1 (16 idx loads) ->
// phase2 (16 row gathers + tail cs/gs gathers) -> sched_barrier(0) ->
// compute. Nothing may cross the barrier, so all ~20 loads stay in flight
// (~160 lines/wave). Grid 4096 for scheduler slack. Everything else = r10:
// 8 lanes/edge, f16 rows (1 line each), pure-DPP red8, 64-wide tail.

typedef _Float16 h2 __attribute__((ext_vector_type(2)));

#if __has_builtin(__builtin_amdgcn_fdot2)
__device__ __forceinline__ float fdot2f(h2 a, h2 b, float c) {
    return __builtin_amdgcn_fdot2(a, b, c, false);
}
#else
__device__ __forceinline__ float fdot2f(h2 a, h2 b, float c) {
    return fmaf((float)a.x, (float)b.x, fmaf((float)a.y, (float)b.y, c));
}
#endif

#if __has_builtin(__builtin_amdgcn_sched_barrier)
#define SCHED_WALL() __builtin_amdgcn_sched_barrier(0)
#else
#define SCHED_WALL() __threadfence_block()  // weaker fallback
#endif

// 8-lane sum, pure DPP (VALU pipe only): xor1, xor2 (quad_perm), half-mirror.
__device__ __forceinline__ float red8(float x) {
    int t;
    t = __builtin_amdgcn_mov_dpp(__float_as_int(x), 0xB1, 0xF, 0xF, true);  // quad_perm [1,0,3,2] = xor1
    x += __int_as_float(t);
    t = __builtin_amdgcn_mov_dpp(__float_as_int(x), 0x4E, 0xF, 0xF, true);  // quad_perm [2,3,0,1] = xor2
    x += __int_as_float(t);
    t = __builtin_amdgcn_mov_dpp(__float_as_int(x), 0x141, 0xF, 0xF, true); // row_half_mirror: xor4 within 8
    x += __int_as_float(t);
    return x;
}

__device__ __forceinline__ unsigned pack2h(float lo, float hi) {
    h2 p = {(_Float16)lo, (_Float16)hi};
    return __builtin_bit_cast(unsigned, p);
}

// ---------------- pack kernel: f32 rows -> f16 rows in d_ws ----------------
__global__ __launch_bounds__(256) void zinb_pack_kernel(
    const float4* __restrict__ c_src, const float4* __restrict__ g_src,
    uint4* __restrict__ c_dst, uint4* __restrict__ g_dst,
    int n_c_groups, int n_total_groups)   // group = 8 floats -> one uint4
{
    const int i = (int)(blockIdx.x * blockDim.x + threadIdx.x);
    if (i >= n_total_groups) return;
    const float4* src; uint4* dst; int j;
    if (i < n_c_groups) { src = c_src; dst = c_dst; j = i; }
    else                { src = g_src; dst = g_dst; j = i - n_c_groups; }
    const float4 a = src[2 * j];
    const float4 b = src[2 * j + 1];
    uint4 o;
    o.x = pack2h(a.x, a.y);
    o.y = pack2h(a.z, a.w);
    o.z = pack2h(b.x, b.y);
    o.w = pack2h(b.z, b.w);
    dst[j] = o;
}

// -------- main kernel: 8 lanes/edge, FORCED deep gather window --------
__global__ __launch_bounds__(256) void zinb_edge_f16_kernel(
    const uint4* __restrict__ c_pack,   // [n_cells][8] uint4 (64 f16)
    const uint4* __restrict__ g_pack,   // [n_genes][8]
    const float* __restrict__ cs_factor,
    const float* __restrict__ gs_factor,
    const int* __restrict__ edge_u,
    const int* __restrict__ edge_v,
    const float* __restrict__ W_mean, const float* __restrict__ b_mean,
    const float* __restrict__ W_disp, const float* __restrict__ b_disp,
    const float* __restrict__ W_pi,   const float* __restrict__ b_pi,
    float* __restrict__ out_mu,
    float* __restrict__ out_disp,
    float* __restrict__ out_pi,
    int n_edges)
{
    const int lane = (int)(threadIdx.x & 63);
    const int k    = lane & 7;    // chunk within row (elements 8k..8k+7)
    const int grp  = lane >> 3;   // edge within octet

    // Per-lane weight fragments for chunk k (fixed for kernel lifetime).
    h2 wm[4], wd[4], wp[4];
    #pragma unroll
    for (int i = 0; i < 4; ++i) {
        wm[i] = (h2){(_Float16)W_mean[8 * k + 2 * i], (_Float16)W_mean[8 * k + 2 * i + 1]};
        wd[i] = (h2){(_Float16)W_disp[8 * k + 2 * i], (_Float16)W_disp[8 * k + 2 * i + 1]};
        wp[i] = (h2){(_Float16)W_pi  [8 * k + 2 * i], (_Float16)W_pi  [8 * k + 2 * i + 1]};
    }
    const float bm = b_mean[0], bd = b_disp[0], bp = b_pi[0];

    const int perm = (k << 3) | grp;          // this lane's tail-edge offset

    int e0 = (int)(blockIdx.x * blockDim.x + threadIdx.x) & ~63;  // wave base
    const int stride = (int)(gridDim.x * blockDim.x);

    for (; e0 < n_edges; e0 += stride) {
        // ---- phase 1: all index loads (coalesced / broadcast) ----
        int ua[8], va[8];
        #pragma unroll
        for (int j = 0; j < 8; ++j) {
            int ej = e0 + 8 * j + grp;
            if (ej >= n_edges) ej = n_edges - 1;   // whole octet clamps together
            ua[j] = edge_u[ej];
            va[j] = edge_v[ej];
        }
        const int et  = e0 + perm;
        const int etc = (et < n_edges) ? et : (n_edges - 1);
        const int ut = edge_u[etc];
        const int vt = edge_v[etc];

        // ---- phase 2: all gathers issued back-to-back ----
        uint4 cu[8], gu[8];
        #pragma unroll
        for (int j = 0; j < 8; ++j) {
            cu[j] = c_pack[(size_t)ua[j] * 8 + k];
            gu[j] = g_pack[(size_t)va[j] * 8 + k];
        }
        const float cs_t = cs_factor[ut];
        const float gs_t = gs_factor[vt];

        // ---- WALL: nothing crosses; all loads above stay in flight ----
        SCHED_WALL();

        // ---- phase 3: 8 compute sub-phases ----
        float pmk = 0.f, pdk = 0.f, ppk = 0.f;

        #pragma unroll
        for (int j = 0; j < 8; ++j) {
            const h2 c0 = __builtin_bit_cast(h2, cu[j].x), g0 = __builtin_bit_cast(h2, gu[j].x);
            const h2 c1 = __builtin_bit_cast(h2, cu[j].y), g1 = __builtin_bit_cast(h2, gu[j].y);
            const h2 c2 = __builtin_bit_cast(h2, cu[j].z), g2 = __builtin_bit_cast(h2, gu[j].z);
            const h2 c3 = __builtin_bit_cast(h2, cu[j].w), g3 = __builtin_bit_cast(h2, gu[j].w);
            const h2 h0 = c0 * g0;                 // v_pk_mul_f16
            const h2 h1 = c1 * g1;
            const h2 hh2 = c2 * g2;
            const h2 h3 = c3 * g3;

            float pm = 0.f, pd = 0.f, pp = 0.f;
            pm = fdot2f(h0, wm[0], pm); pm = fdot2f(h1, wm[1], pm);
            pm = fdot2f(hh2, wm[2], pm); pm = fdot2f(h3, wm[3], pm);
            pd = fdot2f(h0, wd[0], pd); pd = fdot2f(h1, wd[1], pd);
            pd = fdot2f(hh2, wd[2], pd); pd = fdot2f(h3, wd[3], pd);
            pp = fdot2f(h0, wp[0], pp); pp = fdot2f(h1, wp[1], pp);
            pp = fdot2f(hh2, wp[2], pp); pp = fdot2f(h3, wp[3], pp);

            pm = red8(pm);
            pd = red8(pd);
            pp = red8(pp);

            if (k == j) { pmk = pm; pdk = pd; ppk = pp; }  // lane's own edge
        }

        // ---- tail: 64 lanes, one edge each ----
        const float mu_ = __builtin_amdgcn_rcpf(1.f + __expf(-(pmk + bm)));
        const float pi_ = __builtin_amdgcn_rcpf(1.f + __expf(-(ppk + bp)));

        const float sx = gs_t * (pdk + bd);
        const float sp = fmaxf(sx, 0.f) + __logf(1.f + __expf(-fabsf(sx)));
        const float disp = fminf(fmaxf(sp, 1e-4f), 1e4f);

        const float mu = cs_t * fminf(fmaxf(__expf(gs_t * mu_) - 1.f, 1e-5f), 1e6f);

        if (et < n_edges) {
            __builtin_nontemporal_store(mu,   out_mu + et);
            __builtin_nontemporal_store(disp, out_disp + et);
            __builtin_nontemporal_store(pi_,  out_pi + et);
        }
    }
}

// ---------------- f32 fallback (round-3/5 kernel, proven) ----------------
__global__ __launch_bounds__(256) void zinb_edge_f32_kernel(
    const float* __restrict__ c_feat,
    const float* __restrict__ g_feat,
    const float* __restrict__ cs_factor,
    const float* __restrict__ gs_factor,
    const int* __restrict__ edge_u,
    const int* __restrict__ edge_v,
    const float* __restrict__ W_mean, const float* __restrict__ b_mean,
    const float* __restrict__ W_disp, const float* __restrict__ b_disp,
    const float* __restrict__ W_pi,   const float* __restrict__ b_pi,
    float* __restrict__ out_mu,
    float* __restrict__ out_disp,
    float* __restrict__ out_pi,
    int n_edges)
{
    __shared__ float4 wlds[48];
    {
        const int t = threadIdx.x;
        if (t < 48) {
            const int which = t / 16;
            const int kk    = t % 16;
            const float4* src = (which == 0) ? (const float4*)W_mean
                              : (which == 1) ? (const float4*)W_disp
                                             : (const float4*)W_pi;
            wlds[kk * 3 + which] = src[kk];
        }
    }
    __syncthreads();

    const float bm = b_mean[0], bd = b_disp[0], bp = b_pi[0];
    const float4* __restrict__ c4 = (const float4*)c_feat;
    const float4* __restrict__ g4 = (const float4*)g_feat;

    const int tid    = (int)(blockIdx.x * blockDim.x + threadIdx.x);
    const int stride = (int)(gridDim.x * blockDim.x);

    for (int e = tid; e < n_edges; e += stride) {
        const int u = edge_u[e];
        const int v = edge_v[e];
        const float4* __restrict__ cb = c4 + (size_t)u * 16;
        const float4* __restrict__ gb = g4 + (size_t)v * 16;

        float pm = 0.f, pd = 0.f, pp = 0.f;
        #pragma unroll
        for (int kk = 0; kk < 16; ++kk) {
            const float4 cc = cb[kk];
            const float4 gg = gb[kk];
            const float4 wmv = wlds[kk * 3 + 0];
            const float4 wdv = wlds[kk * 3 + 1];
            const float4 wpv = wlds[kk * 3 + 2];
            const float hx = cc.x * gg.x;
            const float hy = cc.y * gg.y;
            const float hz = cc.z * gg.z;
            const float hw = cc.w * gg.w;
            pm = fmaf(hx, wmv.x, fmaf(hy, wmv.y, fmaf(hz, wmv.z, fmaf(hw, wmv.w, pm))));
            pd = fmaf(hx, wdv.x, fmaf(hy, wdv.y, fmaf(hz, wdv.z, fmaf(hw, wdv.w, pd))));
            pp = fmaf(hx, wpv.x, fmaf(hy, wpv.y, fmaf(hz, wpv.z, fmaf(hw, wpv.w, pp))));
        }

        const float gs = gs_factor[v];
        const float cs = cs_factor[u];
        const float mu_ = __builtin_amdgcn_rcpf(1.f + __expf(-(pm + bm)));
        const float pi_ = __builtin_amdgcn_rcpf(1.f + __expf(-(pp + bp)));
        const float sx = gs * (pd + bd);
        const float sp = fmaxf(sx, 0.f) + __logf(1.f + __expf(-fabsf(sx)));
        const float disp = fminf(fmaxf(sp, 1e-4f), 1e4f);
        const float mu = cs * fminf(fmaxf(__expf(gs * mu_) - 1.f, 1e-5f), 1e6f);

        out_mu[e]   = mu;
        out_disp[e] = disp;
        out_pi[e]   = pi_;
    }
}

extern "C" void kernel_launch(void* const* d_in, const int* in_sizes, int n_in,
                              void* d_out, int out_size, void* d_ws, size_t ws_size,
                              hipStream_t stream) {
    const float* c_feat = (const float*)d_in[0];
    const float* g_feat = (const float*)d_in[1];
    const float* cs     = (const float*)d_in[2];
    const float* gs     = (const float*)d_in[3];
    const int*   eu     = (const int*)d_in[4];
    const int*   ev     = (const int*)d_in[5];
    const float* Wm     = (const float*)d_in[6];
    const float* bm     = (const float*)d_in[7];
    const float* Wd     = (const float*)d_in[8];
    const float* bd     = (const float*)d_in[9];
    const float* Wp     = (const float*)d_in[10];
    const float* bp     = (const float*)d_in[11];

    const int E       = in_sizes[4];
    const int n_cells = in_sizes[0] / 64;
    const int n_genes = in_sizes[1] / 64;

    float* out_mu   = (float*)d_out;
    float* out_disp = out_mu + E;
    float* out_pi   = out_mu + 2 * (size_t)E;

    const size_t c_bytes = (size_t)n_cells * 64 * 2;   // f16 rows (128 B each)
    const size_t g_bytes = (size_t)n_genes * 64 * 2;

    if (ws_size >= c_bytes + g_bytes) {
        uint4* c_pack = (uint4*)d_ws;
        uint4* g_pack = (uint4*)((char*)d_ws + c_bytes);

        const int n_c_groups = n_cells * 8;            // 8 floats per group
        const int n_total    = n_c_groups + n_genes * 8;
        dim3 pgrid((n_total + 255) / 256), pblock(256);
        hipLaunchKernelGGL(zinb_pack_kernel, pgrid, pblock, 0, stream,
                           (const float4*)c_feat, (const float4*)g_feat,
                           c_pack, g_pack, n_c_groups, n_total);

        dim3 grid(4096), block(256);
        hipLaunchKernelGGL(zinb_edge_f16_kernel, grid, block, 0, stream,
                           c_pack, g_pack, cs, gs, eu, ev,
                           Wm, bm, Wd, bd, Wp, bp,
                           out_mu, out_disp, out_pi, E);
    } else {
        dim3 grid(2048), block(256);
        hipLaunchKernelGGL(zinb_edge_f32_kernel, grid, block, 0, stream,
                           c_feat, g_feat, cs, gs, eu, ev,
                           Wm, bm, Wd, bd, Wp, bp,
                           out_mu, out_disp, out_pi, E);
    }
}